// Round 4
// baseline (1244.910 us; speedup 1.0000x reference)
//
#include <hip/hip_runtime.h>
#include <hip/hip_bf16.h>

#define E_TOTAL   800000
#define NN        50000
#define DD        128
#define DE        64
#define ZDIM      320
#define KE        192      // edge GEMM K: x_j (128) + e_ij (64)
#define MT        64
#define NBS       196      // scan blocks: 196*256 = 50176 >= NN

typedef short bf16x8 __attribute__((ext_vector_type(8)));
typedef float f32x4  __attribute__((ext_vector_type(4)));

__device__ __forceinline__ unsigned short f2bf(float f) {
    union { float f; unsigned int u; } v; v.f = f;
    unsigned int u = v.u;
    return (unsigned short)((u + 0x7fffu + ((u >> 16) & 1u)) >> 16);
}

__device__ __forceinline__ float bf2f(unsigned short h) {
    union { unsigned u; float f; } v; v.u = ((unsigned)h) << 16; return v.f;
}

__device__ __forceinline__ unsigned pkbf2(float a, float b) {
    __hip_bfloat162 h = __float22bfloat162_rn(make_float2(a, b));
    unsigned u; __builtin_memcpy(&u, &h, 4); return u;
}

__device__ __forceinline__ uint2 pkbf4(float4 v) {
    uint2 r; r.x = pkbf2(v.x, v.y); r.y = pkbf2(v.z, v.w); return r;
}

__device__ __forceinline__ float fast_rcp(float x) {
#if __has_builtin(__builtin_amdgcn_rcpf)
    return __builtin_amdgcn_rcpf(x);
#else
    return 1.0f / x;
#endif
}

// ===================== main path =====================

// out <- x ; hist(dst) ; WtE[n][k]=W[128+k][n'] ; WtN[n][k]=W[k][n']
__global__ void prep_kernel(const float* __restrict__ x,
                            const int* __restrict__ ei,
                            const float* __restrict__ W_f,
                            const float* __restrict__ W_s,
                            unsigned short* __restrict__ WtE,
                            unsigned short* __restrict__ WtN,
                            int* __restrict__ counts,
                            float* __restrict__ out) {
    int id = blockIdx.x * 256 + threadIdx.x;          // grid = NN*DD/4 exactly
    ((float4*)out)[id] = ((const float4*)x)[id];
    if (id < E_TOTAL) atomicAdd(&counts[ei[E_TOTAL + id]], 1);
    if (id < 256 * KE) {
        int n = id / KE, k = id - n * KE;
        int ok = 128 + k;
        float wv = (n < DD) ? W_f[ok * DD + n] : W_s[ok * DD + (n - DD)];
        WtE[id] = f2bf(wv);
    } else if (id < 256 * KE + 256 * DD) {
        int id2 = id - 256 * KE;
        int n = id2 / DD, k = id2 - n * DD;
        float wv = (n < DD) ? W_f[k * DD + n] : W_s[k * DD + (n - DD)];
        WtN[id2] = f2bf(wv);
    }
}

// ---- hierarchical exclusive scan of counts[NN] -> cursor[NN] ----
__global__ void scan_part(const int* __restrict__ counts, int* __restrict__ partial) {
    __shared__ int red[256];
    int t = threadIdx.x, k = blockIdx.x * 256 + t;
    red[t] = (k < NN) ? counts[k] : 0;
    __syncthreads();
    for (int d = 128; d > 0; d >>= 1) {
        if (t < d) red[t] += red[t + d];
        __syncthreads();
    }
    if (t == 0) partial[blockIdx.x] = red[0];
}

__global__ void scan_top(int* __restrict__ partial) {
    __shared__ int s[256];
    int t = threadIdx.x;
    int v = (t < NBS) ? partial[t] : 0;
    s[t] = v; __syncthreads();
    for (int d = 1; d < 256; d <<= 1) {
        int a = (t >= d) ? s[t - d] : 0;
        __syncthreads();
        s[t] += a;
        __syncthreads();
    }
    if (t < NBS) partial[t] = s[t] - v;   // exclusive block offsets
}

__global__ void scan_final(const int* __restrict__ counts,
                           const int* __restrict__ partial,
                           int* __restrict__ cursor) {
    __shared__ int s[256];
    int t = threadIdx.x, k = blockIdx.x * 256 + t;
    int v = (k < NN) ? counts[k] : 0;
    s[t] = v; __syncthreads();
    for (int d = 1; d < 256; d <<= 1) {
        int a = (t >= d) ? s[t - d] : 0;
        __syncthreads();
        s[t] += a;
        __syncthreads();
    }
    if (k < NN) cursor[k] = partial[blockIdx.x] + s[t] - v;
}

// spak[pos] = (dst<<16)|src ; seid[pos] = original edge id
__global__ void scatter_kernel(const int* __restrict__ ei, int* __restrict__ cursor,
                               unsigned* __restrict__ spak, int* __restrict__ seid) {
    int e = blockIdx.x * 256 + threadIdx.x;
    if (e < E_TOTAL) {
        int d = ei[E_TOTAL + e];
        int pos = atomicAdd(&cursor[d], 1);
        spak[pos] = ((unsigned)d << 16) | (unsigned)ei[e];
        seid[pos] = e;
    }
}

// nodeFS[i][0:128] = x_i·W1f + b_f ; [128:256] = x_i·W1s + b_s   (bf16)
__global__ __launch_bounds__(256, 4)
void node_kernel(const float* __restrict__ x,
                 const unsigned short* __restrict__ WtN,
                 const float* __restrict__ bf_, const float* __restrict__ bs_,
                 unsigned short* __restrict__ nodeFS) {
    __shared__ unsigned short A_lds[MT * DD];  // 16 KB
    const int t = threadIdx.x;
    const int m_off = blockIdx.x * MT;
    const int lane = t & 63, w = t >> 6, l15 = lane & 15, quad = lane >> 4;

    #pragma unroll
    for (int it = 0; it < 8; ++it) {
        int idx = it * 256 + t;
        int e = idx >> 5, kq = idx & 31;
        int row = m_off + e; if (row >= NN) row = NN - 1;
        float4 v = ((const float4*)(x + (size_t)row * DD))[kq];
        int g = kq >> 1;
        int col = ((g & ~7) | ((g & 7) ^ (e & 7))) * 8 + (kq & 1) * 4;
        *((uint2*)&A_lds[e * DD + col]) = pkbf4(v);
    }

    f32x4 acc[4][4] = {};
    const int nt0 = 2 * w;
    const unsigned short* Bp[4];
    #pragma unroll
    for (int u = 0; u < 4; ++u) {
        int nt = nt0 + ((u < 2) ? u : (6 + u));
        Bp[u] = WtN + (size_t)(nt * 16 + l15) * DD + quad * 8;
    }
    __syncthreads();

    #pragma unroll
    for (int ks = 0; ks < 4; ++ks) {
        bf16x8 af[4], bfr[4];
        #pragma unroll
        for (int i = 0; i < 4; ++i) {
            int m = i * 16 + l15;
            int g = 4 * ks + quad;
            int col = ((g & ~7) | ((g & 7) ^ (l15 & 7))) * 8;
            af[i] = *((const bf16x8*)&A_lds[m * DD + col]);
        }
        #pragma unroll
        for (int u = 0; u < 4; ++u)
            bfr[u] = *((const bf16x8*)(Bp[u] + ks * 32));
        #pragma unroll
        for (int i = 0; i < 4; ++i)
            #pragma unroll
            for (int u = 0; u < 4; ++u)
                acc[i][u] = __builtin_amdgcn_mfma_f32_16x16x32_bf16(
                    af[i], bfr[u], acc[i][u], 0, 0, 0);
    }

    const int c0 = 32 * w + l15, c1 = c0 + 16;
    const float bf0 = bf_[c0], bs0 = bs_[c0], bf1 = bf_[c1], bs1 = bs_[c1];
    #pragma unroll
    for (int i = 0; i < 4; ++i)
        #pragma unroll
        for (int j = 0; j < 4; ++j) {
            int e = i * 16 + quad * 4 + j;
            int row = m_off + e;
            if (row < NN) {
                unsigned short* p = nodeFS + (size_t)row * 256;
                p[c0]       = f2bf(acc[i][0][j] + bf0);
                p[c1]       = f2bf(acc[i][1][j] + bf1);
                p[128 + c0] = f2bf(acc[i][2][j] + bs0);
                p[128 + c1] = f2bf(acc[i][3][j] + bs1);
            }
        }
}

// Fused gather + K=192 dual-GEMM + node-term add + gate + run-combined scatter.
__global__ __launch_bounds__(256, 6)
void edge_kernel(const float* __restrict__ x,
                 const float* __restrict__ ea,
                 const unsigned short* __restrict__ WtE,
                 const unsigned short* __restrict__ nodeFS,
                 float* __restrict__ out,
                 const unsigned* __restrict__ spak,
                 const int* __restrict__ seid) {
    __shared__ unsigned short A_lds[MT * KE];   // 24576 B
    __shared__ int dst_lds[MT];
    __shared__ int src_lds[MT];
    __shared__ int eid_lds[MT];

    const int t = threadIdx.x;
    const int m_off = blockIdx.x * MT;
    const int lane = t & 63, w = t >> 6, l15 = lane & 15, quad = lane >> 4;

    if (t < MT) {
        unsigned p = spak[m_off + t];
        dst_lds[t] = (int)(p >> 16);
        src_lds[t] = (int)(p & 0xffffu);
    } else if (t < 2 * MT) {
        eid_lds[t - MT] = seid[m_off + t - MT];
    }
    __syncthreads();

    // e_ij -> cols [128,192)
    #pragma unroll
    for (int it = 0; it < 4; ++it) {
        int idx = it * 256 + t;
        int e = idx >> 4, kq = idx & 15;
        float4 v = ((const float4*)(ea + (size_t)eid_lds[e] * DE))[kq];
        int g = 16 + (kq >> 1);
        int col = ((g & ~7) | ((g & 7) ^ (e & 7))) * 8 + (kq & 1) * 4;
        *((uint2*)&A_lds[e * KE + col]) = pkbf4(v);
    }
    // x[src] -> cols [0,128)
    #pragma unroll
    for (int it = 0; it < 8; ++it) {
        int idx = it * 256 + t;
        int e = idx >> 5, kq = idx & 31;
        float4 v = ((const float4*)(x + (size_t)src_lds[e] * DD))[kq];
        int g = kq >> 1;
        int col = ((g & ~7) | ((g & 7) ^ (e & 7))) * 8 + (kq & 1) * 4;
        *((uint2*)&A_lds[e * KE + col]) = pkbf4(v);
    }

    f32x4 acc[4][4] = {};
    const int nt0 = 2 * w;
    const unsigned short* Bp[4];
    #pragma unroll
    for (int u = 0; u < 4; ++u) {
        int nt = nt0 + ((u < 2) ? u : (6 + u));   // {nt0, nt0+1, nt0+8, nt0+9}
        Bp[u] = WtE + (size_t)(nt * 16 + l15) * KE + quad * 8;
    }
    __syncthreads();

    #pragma unroll
    for (int ks = 0; ks < 6; ++ks) {
        bf16x8 af[4], bfr[4];
        #pragma unroll
        for (int i = 0; i < 4; ++i) {
            int m = i * 16 + l15;
            int g = 4 * ks + quad;
            int col = ((g & ~7) | ((g & 7) ^ (l15 & 7))) * 8;
            af[i] = *((const bf16x8*)&A_lds[m * KE + col]);
        }
        #pragma unroll
        for (int u = 0; u < 4; ++u)
            bfr[u] = *((const bf16x8*)(Bp[u] + ks * 32));
        #pragma unroll
        for (int i = 0; i < 4; ++i)
            #pragma unroll
            for (int u = 0; u < 4; ++u)
                acc[i][u] = __builtin_amdgcn_mfma_f32_16x16x32_bf16(
                    af[i], bfr[u], acc[i][u], 0, 0, 0);
    }

    const int c0 = 32 * w + l15, c1 = c0 + 16;

    int d = -1;
    float s0 = 0.f, s1 = 0.f, nf0 = 0.f, ns0 = 0.f, nf1 = 0.f, ns1 = 0.f;
    #pragma unroll
    for (int i = 0; i < 4; ++i)
        #pragma unroll
        for (int j = 0; j < 4; ++j) {
            int e = i * 16 + quad * 4 + j;
            int dd = dst_lds[e];
            if (dd != d) {
                if (d >= 0) {
                    atomicAdd(out + (size_t)d * DD + c0, s0);
                    atomicAdd(out + (size_t)d * DD + c1, s1);
                }
                d = dd; s0 = 0.f; s1 = 0.f;
                const unsigned short* p = nodeFS + (size_t)d * 256;
                nf0 = bf2f(p[c0]);       nf1 = bf2f(p[c1]);
                ns0 = bf2f(p[128 + c0]); ns1 = bf2f(p[128 + c1]);
            }
            float f0  = acc[i][0][j] + nf0;
            float sg0 = acc[i][2][j] + ns0;
            s0 += fast_rcp(1.f + __expf(-f0)) *
                  (fmaxf(sg0, 0.f) + __logf(1.f + __expf(-fabsf(sg0))));
            float f1  = acc[i][1][j] + nf1;
            float sg1 = acc[i][3][j] + ns1;
            s1 += fast_rcp(1.f + __expf(-f1)) *
                  (fmaxf(sg1, 0.f) + __logf(1.f + __expf(-fabsf(sg1))));
        }
    atomicAdd(out + (size_t)d * DD + c0, s0);
    atomicAdd(out + (size_t)d * DD + c1, s1);
}

__global__ void relu_kernel(float* __restrict__ out) {
    int id = blockIdx.x * 256 + threadIdx.x;
    if (id < NN * DD / 4) {
        float4 v = ((float4*)out)[id];
        v.x = fmaxf(v.x, 0.0f); v.y = fmaxf(v.y, 0.0f);
        v.z = fmaxf(v.z, 0.0f); v.w = fmaxf(v.w, 0.0f);
        ((float4*)out)[id] = v;
    }
}

// ===================== fallback path (R2, unsorted, K=320) =====================

__global__ void prep_fb(const float* __restrict__ x,
                        const float* __restrict__ W_f,
                        const float* __restrict__ W_s,
                        unsigned short* __restrict__ Wt,
                        float* __restrict__ out) {
    int id = blockIdx.x * 256 + threadIdx.x;
    if (id < NN * DD / 4)
        ((float4*)out)[id] = ((const float4*)x)[id];
    if (id < 2 * DD * ZDIM) {
        int n = id / ZDIM, k = id - n * ZDIM;
        float wv = (n < DD) ? W_f[k * DD + n] : W_s[k * DD + (n - DD)];
        Wt[n * ZDIM + k] = f2bf(wv);
    }
}

__global__ __launch_bounds__(256, 3)
void edge_fb(const float* __restrict__ x,
             const int* __restrict__ ei,
             const float* __restrict__ ea,
             const unsigned short* __restrict__ Wt,
             const float* __restrict__ bf_,
             const float* __restrict__ bs_,
             float* __restrict__ out) {
    __shared__ unsigned short A_lds[MT * ZDIM];
    __shared__ int dst_lds[MT];
    __shared__ int src_lds[MT];

    const int t = threadIdx.x;
    const int m_off = blockIdx.x * MT;
    const int lane = t & 63, w = t >> 6, l15 = lane & 15, quad = lane >> 4;

    if (t < MT) dst_lds[t] = ei[E_TOTAL + m_off + t];
    else if (t < 2 * MT) src_lds[t - MT] = ei[m_off + (t - MT)];
    __syncthreads();

    #pragma unroll
    for (int it = 0; it < 4; ++it) {
        int idx = it * 256 + t;
        int e = idx >> 4, kq = idx & 15;
        float4 v = ((const float4*)(ea + (size_t)(m_off + e) * DE))[kq];
        int g = 32 + (kq >> 1);
        int col = ((g & ~7) | ((g & 7) ^ (e & 7))) * 8 + (kq & 1) * 4;
        *((uint2*)&A_lds[e * ZDIM + col]) = pkbf4(v);
    }
    #pragma unroll
    for (int it = 0; it < 8; ++it) {
        int idx = it * 256 + t;
        int e = idx >> 5, kq = idx & 31;
        float4 v = ((const float4*)(x + (size_t)dst_lds[e] * DD))[kq];
        int g = kq >> 1;
        int col = ((g & ~7) | ((g & 7) ^ (e & 7))) * 8 + (kq & 1) * 4;
        *((uint2*)&A_lds[e * ZDIM + col]) = pkbf4(v);
    }
    #pragma unroll
    for (int it = 0; it < 8; ++it) {
        int idx = it * 256 + t;
        int e = idx >> 5, kq = idx & 31;
        float4 v = ((const float4*)(x + (size_t)src_lds[e] * DD))[kq];
        int g = 16 + (kq >> 1);
        int col = ((g & ~7) | ((g & 7) ^ (e & 7))) * 8 + (kq & 1) * 4;
        *((uint2*)&A_lds[e * ZDIM + col]) = pkbf4(v);
    }

    f32x4 acc[4][4] = {};
    const int nt0 = 2 * w;
    const unsigned short* Bp[4];
    #pragma unroll
    for (int u = 0; u < 4; ++u) {
        int nt = nt0 + ((u < 2) ? u : (6 + u));
        Bp[u] = Wt + (size_t)(nt * 16 + l15) * ZDIM + quad * 8;
    }
    __syncthreads();

    #pragma unroll
    for (int ks = 0; ks < 10; ++ks) {
        bf16x8 af[4], bfr[4];
        #pragma unroll
        for (int i = 0; i < 4; ++i) {
            int m = i * 16 + l15;
            int g = 4 * ks + quad;
            int col = ((g & ~7) | ((g & 7) ^ (l15 & 7))) * 8;
            af[i] = *((const bf16x8*)&A_lds[m * ZDIM + col]);
        }
        #pragma unroll
        for (int u = 0; u < 4; ++u)
            bfr[u] = *((const bf16x8*)(Bp[u] + ks * 32));
        #pragma unroll
        for (int i = 0; i < 4; ++i)
            #pragma unroll
            for (int u = 0; u < 4; ++u)
                acc[i][u] = __builtin_amdgcn_mfma_f32_16x16x32_bf16(
                    af[i], bfr[u], acc[i][u], 0, 0, 0);
    }

    const int c0 = 32 * w + l15, c1 = c0 + 16;
    const float bf0 = bf_[c0], bs0 = bs_[c0], bf1 = bf_[c1], bs1 = bs_[c1];
    #pragma unroll
    for (int i = 0; i < 4; ++i)
        #pragma unroll
        for (int j = 0; j < 4; ++j) {
            int e = i * 16 + quad * 4 + j;
            float* op = out + (size_t)dst_lds[e] * DD;
            float f0 = acc[i][0][j] + bf0;
            float sg0 = acc[i][2][j] + bs0;
            atomicAdd(op + c0, fast_rcp(1.f + __expf(-f0)) *
                (fmaxf(sg0, 0.f) + __logf(1.f + __expf(-fabsf(sg0)))));
            float f1 = acc[i][1][j] + bf1;
            float sg1 = acc[i][3][j] + bs1;
            atomicAdd(op + c1, fast_rcp(1.f + __expf(-f1)) *
                (fmaxf(sg1, 0.f) + __logf(1.f + __expf(-fabsf(sg1)))));
        }
}

// ===================== launch =====================

extern "C" void kernel_launch(void* const* d_in, const int* in_sizes, int n_in,
                              void* d_out, int out_size, void* d_ws, size_t ws_size,
                              hipStream_t stream) {
    (void)in_sizes; (void)n_in; (void)out_size;
    const float* x   = (const float*)d_in[0];
    const int*   ei  = (const int*)d_in[1];
    const float* ea  = (const float*)d_in[2];
    const float* W_f = (const float*)d_in[3];
    const float* b_f = (const float*)d_in[4];
    const float* W_s = (const float*)d_in[5];
    const float* b_s = (const float*)d_in[6];
    float* out = (float*)d_out;

    char* ws = (char*)d_ws;
    unsigned short* WtE    = (unsigned short*)ws;              //  98304
    unsigned short* WtN    = (unsigned short*)(ws + 98304);    //  65536
    int*            counts = (int*)(ws + 163840);              // 200000
    int*            cursor = (int*)(ws + 363840);              // 200000
    int*            partial= (int*)(ws + 563840);              //   1024
    unsigned*       spak   = (unsigned*)(ws + 564864);         // 3.2e6
    int*            seid   = (int*)(ws + 3764864);             // 3.2e6
    unsigned short* nodeFS = (unsigned short*)(ws + 6964864);  // 25.6e6
    const size_t WS_NEED = 32564864;

    if (ws_size >= WS_NEED) {
        hipMemsetAsync(counts, 0, NN * sizeof(int), stream);
        prep_kernel<<<NN * DD / 4 / 256, 256, 0, stream>>>(
            x, ei, W_f, W_s, WtE, WtN, counts, out);
        scan_part<<<NBS, 256, 0, stream>>>(counts, partial);
        scan_top<<<1, 256, 0, stream>>>(partial);
        scan_final<<<NBS, 256, 0, stream>>>(counts, partial, cursor);
        scatter_kernel<<<(E_TOTAL + 255) / 256, 256, 0, stream>>>(ei, cursor, spak, seid);
        node_kernel<<<(NN + MT - 1) / MT, 256, 0, stream>>>(x, WtN, b_f, b_s, nodeFS);
        edge_kernel<<<E_TOTAL / MT, 256, 0, stream>>>(
            x, ea, WtE, nodeFS, out, spak, seid);
    } else {
        unsigned short* Wt = (unsigned short*)ws;   // 163840 B
        prep_fb<<<6250, 256, 0, stream>>>(x, W_f, W_s, Wt, out);
        edge_fb<<<E_TOTAL / MT, 256, 0, stream>>>(x, ei, ea, Wt, b_f, b_s, out);
    }

    relu_kernel<<<6250, 256, 0, stream>>>(out);
}

// Round 5
// 662.428 us; speedup vs baseline: 1.8793x; 1.8793x over previous
//
#include <hip/hip_runtime.h>
#include <hip/hip_bf16.h>

#define E_TOTAL   800000
#define NN        50000
#define DD        128
#define DE        64
#define ZDIM      320
#define KE        192      // edge GEMM K: x_j (128) + e_ij (64)
#define MT        64
#define NBS       196      // scan blocks: 196*256 = 50176 >= NN

typedef short bf16x8 __attribute__((ext_vector_type(8)));
typedef float f32x4  __attribute__((ext_vector_type(4)));

__device__ __forceinline__ unsigned short f2bf(float f) {
    union { float f; unsigned int u; } v; v.f = f;
    unsigned int u = v.u;
    return (unsigned short)((u + 0x7fffu + ((u >> 16) & 1u)) >> 16);
}

__device__ __forceinline__ float bf2f(unsigned short h) {
    union { unsigned u; float f; } v; v.u = ((unsigned)h) << 16; return v.f;
}

__device__ __forceinline__ unsigned pkbf2(float a, float b) {
    __hip_bfloat162 h = __float22bfloat162_rn(make_float2(a, b));
    unsigned u; __builtin_memcpy(&u, &h, 4); return u;
}

__device__ __forceinline__ uint2 pkbf4(float4 v) {
    uint2 r; r.x = pkbf2(v.x, v.y); r.y = pkbf2(v.z, v.w); return r;
}

__device__ __forceinline__ float fast_rcp(float x) {
#if __has_builtin(__builtin_amdgcn_rcpf)
    return __builtin_amdgcn_rcpf(x);
#else
    return 1.0f / x;
#endif
}

// ===================== main path =====================

// out <- x ; hist(dst) ; WtE[n][k]=W[128+k][n'] ; WtN[n][k]=W[k][n']
__global__ void prep_kernel(const float* __restrict__ x,
                            const int* __restrict__ ei,
                            const float* __restrict__ W_f,
                            const float* __restrict__ W_s,
                            unsigned short* __restrict__ WtE,
                            unsigned short* __restrict__ WtN,
                            int* __restrict__ counts,
                            float* __restrict__ out) {
    int id = blockIdx.x * 256 + threadIdx.x;          // grid = NN*DD/4 exactly
    ((float4*)out)[id] = ((const float4*)x)[id];
    if (id < E_TOTAL) atomicAdd(&counts[ei[E_TOTAL + id]], 1);
    if (id < 256 * KE) {
        int n = id / KE, k = id - n * KE;
        int ok = 128 + k;
        float wv = (n < DD) ? W_f[ok * DD + n] : W_s[ok * DD + (n - DD)];
        WtE[id] = f2bf(wv);
    } else if (id < 256 * KE + 256 * DD) {
        int id2 = id - 256 * KE;
        int n = id2 / DD, k = id2 - n * DD;
        float wv = (n < DD) ? W_f[k * DD + n] : W_s[k * DD + (n - DD)];
        WtN[id2] = f2bf(wv);
    }
}

// ---- hierarchical exclusive scan of counts[NN] -> cursor[NN] ----
__global__ void scan_part(const int* __restrict__ counts, int* __restrict__ partial) {
    __shared__ int red[256];
    int t = threadIdx.x, k = blockIdx.x * 256 + t;
    red[t] = (k < NN) ? counts[k] : 0;
    __syncthreads();
    for (int d = 128; d > 0; d >>= 1) {
        if (t < d) red[t] += red[t + d];
        __syncthreads();
    }
    if (t == 0) partial[blockIdx.x] = red[0];
}

__global__ void scan_top(int* __restrict__ partial) {
    __shared__ int s[256];
    int t = threadIdx.x;
    int v = (t < NBS) ? partial[t] : 0;
    s[t] = v; __syncthreads();
    for (int d = 1; d < 256; d <<= 1) {
        int a = (t >= d) ? s[t - d] : 0;
        __syncthreads();
        s[t] += a;
        __syncthreads();
    }
    if (t < NBS) partial[t] = s[t] - v;   // exclusive block offsets
}

__global__ void scan_final(const int* __restrict__ counts,
                           const int* __restrict__ partial,
                           int* __restrict__ cursor) {
    __shared__ int s[256];
    int t = threadIdx.x, k = blockIdx.x * 256 + t;
    int v = (k < NN) ? counts[k] : 0;
    s[t] = v; __syncthreads();
    for (int d = 1; d < 256; d <<= 1) {
        int a = (t >= d) ? s[t - d] : 0;
        __syncthreads();
        s[t] += a;
        __syncthreads();
    }
    if (k < NN) cursor[k] = partial[blockIdx.x] + s[t] - v;
}

// spak2[pos] = { (dst<<16)|src , eid }  — single 8-B store
__global__ void scatter_kernel(const int* __restrict__ ei, int* __restrict__ cursor,
                               uint2* __restrict__ spak2) {
    int e = blockIdx.x * 256 + threadIdx.x;
    if (e < E_TOTAL) {
        int d = ei[E_TOTAL + e];
        int pos = atomicAdd(&cursor[d], 1);
        uint2 p; p.x = ((unsigned)d << 16) | (unsigned)ei[e]; p.y = (unsigned)e;
        spak2[pos] = p;
    }
}

// nodeP: per node 256 ushorts laid out [wave w][lane l15][f_c0,f_c1,s_c0,s_c1]
// (c0 = 32w + l15, c1 = c0+16) so the edge epilogue reads one coalesced uint2.
__global__ __launch_bounds__(256, 4)
void node_kernel(const float* __restrict__ x,
                 const unsigned short* __restrict__ WtN,
                 const float* __restrict__ bf_, const float* __restrict__ bs_,
                 unsigned short* __restrict__ nodeP) {
    __shared__ unsigned short A_lds[MT * DD];  // 16 KB
    const int t = threadIdx.x;
    const int m_off = blockIdx.x * MT;
    const int lane = t & 63, w = t >> 6, l15 = lane & 15, quad = lane >> 4;

    #pragma unroll
    for (int it = 0; it < 8; ++it) {
        int idx = it * 256 + t;
        int e = idx >> 5, kq = idx & 31;
        int row = m_off + e; if (row >= NN) row = NN - 1;
        float4 v = ((const float4*)(x + (size_t)row * DD))[kq];
        int g = kq >> 1;
        int col = ((g & ~7) | ((g & 7) ^ (e & 7))) * 8 + (kq & 1) * 4;
        *((uint2*)&A_lds[e * DD + col]) = pkbf4(v);
    }

    f32x4 acc[4][4] = {};
    const int nt0 = 2 * w;
    const unsigned short* Bp[4];
    #pragma unroll
    for (int u = 0; u < 4; ++u) {
        int nt = nt0 + ((u < 2) ? u : (6 + u));
        Bp[u] = WtN + (size_t)(nt * 16 + l15) * DD + quad * 8;
    }
    __syncthreads();

    #pragma unroll
    for (int ks = 0; ks < 4; ++ks) {
        bf16x8 af[4], bfr[4];
        #pragma unroll
        for (int i = 0; i < 4; ++i) {
            int m = i * 16 + l15;
            int g = 4 * ks + quad;
            int col = ((g & ~7) | ((g & 7) ^ (l15 & 7))) * 8;
            af[i] = *((const bf16x8*)&A_lds[m * DD + col]);
        }
        #pragma unroll
        for (int u = 0; u < 4; ++u)
            bfr[u] = *((const bf16x8*)(Bp[u] + ks * 32));
        #pragma unroll
        for (int i = 0; i < 4; ++i)
            #pragma unroll
            for (int u = 0; u < 4; ++u)
                acc[i][u] = __builtin_amdgcn_mfma_f32_16x16x32_bf16(
                    af[i], bfr[u], acc[i][u], 0, 0, 0);
    }

    const int c0 = 32 * w + l15, c1 = c0 + 16;
    const float bf0 = bf_[c0], bs0 = bs_[c0], bf1 = bf_[c1], bs1 = bs_[c1];
    #pragma unroll
    for (int i = 0; i < 4; ++i)
        #pragma unroll
        for (int j = 0; j < 4; ++j) {
            int e = i * 16 + quad * 4 + j;
            int row = m_off + e;
            if (row < NN) {
                uint2 pk;
                pk.x = pkbf2(acc[i][0][j] + bf0, acc[i][1][j] + bf1);
                pk.y = pkbf2(acc[i][2][j] + bs0, acc[i][3][j] + bs1);
                *((uint2*)(nodeP + (size_t)row * 256 + w * 64 + l15 * 4)) = pk;
            }
        }
}

// Fused gather + K=192 dual-GEMM + node-term add + gate + run-combined scatter.
// __launch_bounds__(256,4): 128-reg budget — MUST NOT spill (R4 lesson: (256,6)
// forced an ~85-reg cap -> scratch spill -> 2 GB of HBM traffic).
__global__ __launch_bounds__(256, 4)
void edge_kernel(const float* __restrict__ x,
                 const float* __restrict__ ea,
                 const unsigned short* __restrict__ WtE,
                 const unsigned short* __restrict__ nodeP,
                 float* __restrict__ out,
                 const uint2* __restrict__ spak2) {
    __shared__ unsigned short A_lds[MT * KE];   // 24576 B
    __shared__ int dst_lds[MT];
    __shared__ int src_lds[MT];
    __shared__ int eid_lds[MT];

    const int t = threadIdx.x;
    const int m_off = blockIdx.x * MT;
    const int lane = t & 63, w = t >> 6, l15 = lane & 15, quad = lane >> 4;

    if (t < MT) {
        uint2 p = spak2[m_off + t];
        dst_lds[t] = (int)(p.x >> 16);
        src_lds[t] = (int)(p.x & 0xffffu);
        eid_lds[t] = (int)p.y;
    }
    __syncthreads();

    // e_ij -> cols [128,192)
    #pragma unroll
    for (int it = 0; it < 4; ++it) {
        int idx = it * 256 + t;
        int e = idx >> 4, kq = idx & 15;
        float4 v = ((const float4*)(ea + (size_t)eid_lds[e] * DE))[kq];
        int g = 16 + (kq >> 1);
        int col = ((g & ~7) | ((g & 7) ^ (e & 7))) * 8 + (kq & 1) * 4;
        *((uint2*)&A_lds[e * KE + col]) = pkbf4(v);
    }
    // x[src] -> cols [0,128)
    #pragma unroll
    for (int it = 0; it < 8; ++it) {
        int idx = it * 256 + t;
        int e = idx >> 5, kq = idx & 31;
        float4 v = ((const float4*)(x + (size_t)src_lds[e] * DD))[kq];
        int g = kq >> 1;
        int col = ((g & ~7) | ((g & 7) ^ (e & 7))) * 8 + (kq & 1) * 4;
        *((uint2*)&A_lds[e * KE + col]) = pkbf4(v);
    }

    f32x4 acc[4][4] = {};
    const int nt0 = 2 * w;
    const unsigned short* Bp[4];
    #pragma unroll
    for (int u = 0; u < 4; ++u) {
        int nt = nt0 + ((u < 2) ? u : (6 + u));   // {nt0, nt0+1, nt0+8, nt0+9}
        Bp[u] = WtE + (size_t)(nt * 16 + l15) * KE + quad * 8;
    }
    __syncthreads();

    #pragma unroll
    for (int ks = 0; ks < 6; ++ks) {
        bf16x8 af[4], bfr[4];
        #pragma unroll
        for (int i = 0; i < 4; ++i) {
            int m = i * 16 + l15;
            int g = 4 * ks + quad;
            int col = ((g & ~7) | ((g & 7) ^ (l15 & 7))) * 8;
            af[i] = *((const bf16x8*)&A_lds[m * KE + col]);
        }
        #pragma unroll
        for (int u = 0; u < 4; ++u)
            bfr[u] = *((const bf16x8*)(Bp[u] + ks * 32));
        #pragma unroll
        for (int i = 0; i < 4; ++i)
            #pragma unroll
            for (int u = 0; u < 4; ++u)
                acc[i][u] = __builtin_amdgcn_mfma_f32_16x16x32_bf16(
                    af[i], bfr[u], acc[i][u], 0, 0, 0);
    }

    const int c0 = 32 * w + l15, c1 = c0 + 16;
    const int np_off = w * 64 + l15 * 4;

    int d = -1;
    float s0 = 0.f, s1 = 0.f, nf0 = 0.f, ns0 = 0.f, nf1 = 0.f, ns1 = 0.f;
    #pragma unroll
    for (int i = 0; i < 4; ++i)
        #pragma unroll
        for (int j = 0; j < 4; ++j) {
            int e = i * 16 + quad * 4 + j;
            int dd = dst_lds[e];
            if (dd != d) {
                if (d >= 0) {
                    atomicAdd(out + (size_t)d * DD + c0, s0);
                    atomicAdd(out + (size_t)d * DD + c1, s1);
                }
                d = dd; s0 = 0.f; s1 = 0.f;
                uint2 pk = *((const uint2*)(nodeP + (size_t)d * 256 + np_off));
                nf0 = bf2f((unsigned short)(pk.x & 0xffffu));
                nf1 = bf2f((unsigned short)(pk.x >> 16));
                ns0 = bf2f((unsigned short)(pk.y & 0xffffu));
                ns1 = bf2f((unsigned short)(pk.y >> 16));
            }
            float f0  = acc[i][0][j] + nf0;
            float sg0 = acc[i][2][j] + ns0;
            s0 += fast_rcp(1.f + __expf(-f0)) *
                  (fmaxf(sg0, 0.f) + __logf(1.f + __expf(-fabsf(sg0))));
            float f1  = acc[i][1][j] + nf1;
            float sg1 = acc[i][3][j] + ns1;
            s1 += fast_rcp(1.f + __expf(-f1)) *
                  (fmaxf(sg1, 0.f) + __logf(1.f + __expf(-fabsf(sg1))));
        }
    atomicAdd(out + (size_t)d * DD + c0, s0);
    atomicAdd(out + (size_t)d * DD + c1, s1);
}

__global__ void relu_kernel(float* __restrict__ out) {
    int id = blockIdx.x * 256 + threadIdx.x;
    if (id < NN * DD / 4) {
        float4 v = ((float4*)out)[id];
        v.x = fmaxf(v.x, 0.0f); v.y = fmaxf(v.y, 0.0f);
        v.z = fmaxf(v.z, 0.0f); v.w = fmaxf(v.w, 0.0f);
        ((float4*)out)[id] = v;
    }
}

// ===================== fallback path (R2, unsorted, K=320) =====================

__global__ void prep_fb(const float* __restrict__ x,
                        const float* __restrict__ W_f,
                        const float* __restrict__ W_s,
                        unsigned short* __restrict__ Wt,
                        float* __restrict__ out) {
    int id = blockIdx.x * 256 + threadIdx.x;
    if (id < NN * DD / 4)
        ((float4*)out)[id] = ((const float4*)x)[id];
    if (id < 2 * DD * ZDIM) {
        int n = id / ZDIM, k = id - n * ZDIM;
        float wv = (n < DD) ? W_f[k * DD + n] : W_s[k * DD + (n - DD)];
        Wt[n * ZDIM + k] = f2bf(wv);
    }
}

__global__ __launch_bounds__(256, 3)
void edge_fb(const float* __restrict__ x,
             const int* __restrict__ ei,
             const float* __restrict__ ea,
             const unsigned short* __restrict__ Wt,
             const float* __restrict__ bf_,
             const float* __restrict__ bs_,
             float* __restrict__ out) {
    __shared__ unsigned short A_lds[MT * ZDIM];
    __shared__ int dst_lds[MT];
    __shared__ int src_lds[MT];

    const int t = threadIdx.x;
    const int m_off = blockIdx.x * MT;
    const int lane = t & 63, w = t >> 6, l15 = lane & 15, quad = lane >> 4;

    if (t < MT) dst_lds[t] = ei[E_TOTAL + m_off + t];
    else if (t < 2 * MT) src_lds[t - MT] = ei[m_off + (t - MT)];
    __syncthreads();

    #pragma unroll
    for (int it = 0; it < 4; ++it) {
        int idx = it * 256 + t;
        int e = idx >> 4, kq = idx & 15;
        float4 v = ((const float4*)(ea + (size_t)(m_off + e) * DE))[kq];
        int g = 32 + (kq >> 1);
        int col = ((g & ~7) | ((g & 7) ^ (e & 7))) * 8 + (kq & 1) * 4;
        *((uint2*)&A_lds[e * ZDIM + col]) = pkbf4(v);
    }
    #pragma unroll
    for (int it = 0; it < 8; ++it) {
        int idx = it * 256 + t;
        int e = idx >> 5, kq = idx & 31;
        float4 v = ((const float4*)(x + (size_t)dst_lds[e] * DD))[kq];
        int g = kq >> 1;
        int col = ((g & ~7) | ((g & 7) ^ (e & 7))) * 8 + (kq & 1) * 4;
        *((uint2*)&A_lds[e * ZDIM + col]) = pkbf4(v);
    }
    #pragma unroll
    for (int it = 0; it < 8; ++it) {
        int idx = it * 256 + t;
        int e = idx >> 5, kq = idx & 31;
        float4 v = ((const float4*)(x + (size_t)src_lds[e] * DD))[kq];
        int g = 16 + (kq >> 1);
        int col = ((g & ~7) | ((g & 7) ^ (e & 7))) * 8 + (kq & 1) * 4;
        *((uint2*)&A_lds[e * ZDIM + col]) = pkbf4(v);
    }

    f32x4 acc[4][4] = {};
    const int nt0 = 2 * w;
    const unsigned short* Bp[4];
    #pragma unroll
    for (int u = 0; u < 4; ++u) {
        int nt = nt0 + ((u < 2) ? u : (6 + u));
        Bp[u] = Wt + (size_t)(nt * 16 + l15) * ZDIM + quad * 8;
    }
    __syncthreads();

    #pragma unroll
    for (int ks = 0; ks < 10; ++ks) {
        bf16x8 af[4], bfr[4];
        #pragma unroll
        for (int i = 0; i < 4; ++i) {
            int m = i * 16 + l15;
            int g = 4 * ks + quad;
            int col = ((g & ~7) | ((g & 7) ^ (l15 & 7))) * 8;
            af[i] = *((const bf16x8*)&A_lds[m * ZDIM + col]);
        }
        #pragma unroll
        for (int u = 0; u < 4; ++u)
            bfr[u] = *((const bf16x8*)(Bp[u] + ks * 32));
        #pragma unroll
        for (int i = 0; i < 4; ++i)
            #pragma unroll
            for (int u = 0; u < 4; ++u)
                acc[i][u] = __builtin_amdgcn_mfma_f32_16x16x32_bf16(
                    af[i], bfr[u], acc[i][u], 0, 0, 0);
    }

    const int c0 = 32 * w + l15, c1 = c0 + 16;
    const float bf0 = bf_[c0], bs0 = bs_[c0], bf1 = bf_[c1], bs1 = bs_[c1];
    #pragma unroll
    for (int i = 0; i < 4; ++i)
        #pragma unroll
        for (int j = 0; j < 4; ++j) {
            int e = i * 16 + quad * 4 + j;
            float* op = out + (size_t)dst_lds[e] * DD;
            float f0 = acc[i][0][j] + bf0;
            float sg0 = acc[i][2][j] + bs0;
            atomicAdd(op + c0, fast_rcp(1.f + __expf(-f0)) *
                (fmaxf(sg0, 0.f) + __logf(1.f + __expf(-fabsf(sg0)))));
            float f1 = acc[i][1][j] + bf1;
            float sg1 = acc[i][3][j] + bs1;
            atomicAdd(op + c1, fast_rcp(1.f + __expf(-f1)) *
                (fmaxf(sg1, 0.f) + __logf(1.f + __expf(-fabsf(sg1)))));
        }
}

// ===================== launch =====================

extern "C" void kernel_launch(void* const* d_in, const int* in_sizes, int n_in,
                              void* d_out, int out_size, void* d_ws, size_t ws_size,
                              hipStream_t stream) {
    (void)in_sizes; (void)n_in; (void)out_size;
    const float* x   = (const float*)d_in[0];
    const int*   ei  = (const int*)d_in[1];
    const float* ea  = (const float*)d_in[2];
    const float* W_f = (const float*)d_in[3];
    const float* b_f = (const float*)d_in[4];
    const float* W_s = (const float*)d_in[5];
    const float* b_s = (const float*)d_in[6];
    float* out = (float*)d_out;

    char* ws = (char*)d_ws;
    unsigned short* WtE    = (unsigned short*)ws;              //  98304
    unsigned short* WtN    = (unsigned short*)(ws + 98304);    //  65536
    int*            counts = (int*)(ws + 163840);              // 200000
    int*            cursor = (int*)(ws + 363840);              // 200000
    int*            partial= (int*)(ws + 563840);              //   1024
    uint2*          spak2  = (uint2*)(ws + 564864);            // 6.4e6
    unsigned short* nodeP  = (unsigned short*)(ws + 6964864);  // 25.6e6
    const size_t WS_NEED = 32564864;

    if (ws_size >= WS_NEED) {
        hipMemsetAsync(counts, 0, NN * sizeof(int), stream);
        prep_kernel<<<NN * DD / 4 / 256, 256, 0, stream>>>(
            x, ei, W_f, W_s, WtE, WtN, counts, out);
        scan_part<<<NBS, 256, 0, stream>>>(counts, partial);
        scan_top<<<1, 256, 0, stream>>>(partial);
        scan_final<<<NBS, 256, 0, stream>>>(counts, partial, cursor);
        scatter_kernel<<<(E_TOTAL + 255) / 256, 256, 0, stream>>>(ei, cursor, spak2);
        node_kernel<<<(NN + MT - 1) / MT, 256, 0, stream>>>(x, WtN, b_f, b_s, nodeP);
        edge_kernel<<<E_TOTAL / MT, 256, 0, stream>>>(
            x, ea, WtE, nodeP, out, spak2);
    } else {
        unsigned short* Wt = (unsigned short*)ws;   // 163840 B
        prep_fb<<<6250, 256, 0, stream>>>(x, W_f, W_s, Wt, out);
        edge_fb<<<E_TOTAL / MT, 256, 0, stream>>>(x, ei, ea, Wt, b_f, b_s, out);
    }

    relu_kernel<<<6250, 256, 0, stream>>>(out);
}